// Round 4
// baseline (195.505 us; speedup 1.0000x reference)
//
#include <hip/hip_runtime.h>
#include <hip/hip_bf16.h>
#include <math.h>

typedef short s8v __attribute__((ext_vector_type(8)));
typedef float f4v __attribute__((ext_vector_type(4)));

#define HH 256
#define TP 32              // points per block: 2 pipelined groups of 16
#define NTHREADS 256
// LDS strides in SHORTS. ks-chunk = 64 rows * 8 shorts + 8 pad = 520 (1040 B;
// 16 B rotation per ks spreads banks -> conflict-free b64 scatter writes)
#define KSTR 520
#define TSTR 4160          // 8 * KSTR: one A-tile (16 pts x 256 feats, frag-linear)
#define NTILES 3           // 3 streams x 1 point-group per plane
#define PLANE (NTILES * TSTR)   // 12480 shorts = 25.0 KB; 2 planes = 49.9 KB

__device__ __forceinline__ unsigned short bf_rne(float x){
    union{float f;unsigned u;}v; v.f=x;
    unsigned r = v.u + 0x7FFFu + ((v.u >> 16) & 1u);
    return (unsigned short)(r >> 16);
}
// RNE-pack two floats -> packed bf16x2 (lowers to v_cvt_pk_bf16_f32 on gfx950)
__device__ __forceinline__ unsigned pack_rne2(float a, float b){
    union { __hip_bfloat162 h; unsigned u; } v;
    v.h = __float22bfloat162_rn(float2{a, b});
    return v.u;
}

// ---- prep: B-fragments for W1..W3 (single RNE bf16 plane) with k-permutation
// pi folded in, plus pi-ordered fp32 planes for W0 cols, b0.  (unchanged)
__global__ __launch_bounds__(256)
void prep_weights(const float* __restrict__ W1, const float* __restrict__ W2,
                  const float* __restrict__ W3, const float* __restrict__ W0,
                  const float* __restrict__ b0, const float* __restrict__ W4,
                  unsigned short* __restrict__ wsB, float* __restrict__ wsF)
{
    int t = blockIdx.x * 256 + threadIdx.x;
    if (t < 24576) {
        int layer = t >> 13;
        int rem = t & 8191;
        int l  = rem & 63;
        int ks = (rem >> 6) & 7;
        int nt = rem >> 9;
        const float* W = (layer == 0) ? W1 : (layer == 1) ? W2 : W3;
        int n_out = nt * 16 + (l & 15);
        int quad  = l >> 4;
        const float* row = W + n_out * HH;
        s8v hi;
        #pragma unroll
        for (int j = 0; j < 8; ++j) {
            int n_in = quad * 64 + (j & 3) * 16 + ((j >> 2) << 3) + ks;
            hi[j] = (short)bf_rne(row[n_in]);
        }
        int dst = ((nt * 8 + ks) * 64 + l) * 8;
        *(s8v*)(wsB + layer * 65536 + dst) = hi;
    } else if (t < 24832) {
        int n = t - 24576;
        int pos = ((n & 7) * 4 + (n >> 6)) * 8 + ((n >> 4) & 3) + 4 * ((n >> 3) & 1);
        wsF[pos]       = W0[2 * n];
        wsF[256 + pos] = W0[2 * n + 1];
        wsF[512 + pos] = b0[n];
        wsF[768 + pos] = W4[n];
    }
}

// ---- MFMA for one group/layer: 12 MFMAs/ks reading plane at byte-base PB ----
#define MFMA_LAYER(ACC, PB, WLH, BL) do {                                   \
    _Pragma("unroll")                                                       \
    for (int i_ = 0; i_ < 4; ++i_) {                                        \
        float bias_ = (BL)[w * 64 + i_ * 16 + m16];                         \
        (ACC)[0][i_] = (f4v){bias_, bias_, bias_, bias_};                   \
        (ACC)[1][i_] = (f4v){0.f, 0.f, 0.f, 0.f};                           \
        (ACC)[2][i_] = (f4v){0.f, 0.f, 0.f, 0.f};                           \
    }                                                                       \
    __builtin_amdgcn_s_setprio(1);                                          \
    _Pragma("unroll")                                                       \
    for (int ks_ = 0; ks_ < 8; ++ks_) {                                     \
        s8v ah_[NTILES];                                                    \
        const int aoff_ = (PB) + ks_ * KSTR + lane * 8;                     \
        _Pragma("unroll")                                                   \
        for (int t_ = 0; t_ < NTILES; ++t_)                                 \
            ah_[t_] = *(const s8v*)&Ahi[t_ * TSTR + aoff_];                 \
        _Pragma("unroll")                                                   \
        for (int i_ = 0; i_ < 4; ++i_) {                                    \
            const int off_ = (((w * 4 + i_) * 8 + ks_) * 64 + lane) * 8;    \
            s8v bh_ = *(const s8v*)((WLH) + off_);                          \
            _Pragma("unroll")                                               \
            for (int t_ = 0; t_ < NTILES; ++t_)                             \
                (ACC)[t_][i_] = __builtin_amdgcn_mfma_f32_16x16x32_bf16(    \
                    ah_[t_], bh_, (ACC)[t_][i_], 0, 0, 0);                  \
        }                                                                   \
    }                                                                       \
    __builtin_amdgcn_s_setprio(0);                                          \
} while (0)

// ---- tanh-transform of acc + pi-scatter back into plane at base PB ----
#define TRANSFORM(ACC, PB) do {                                             \
    const int ksw_  = m16 & 7;                                              \
    const int hsel_ = m16 >> 3;                                             \
    const int wbase_ = (PB) + ksw_ * KSTR + (16 * w + q * 4) * 8 + 4 * hsel_; \
    _Pragma("unroll")                                                       \
    for (int r_ = 0; r_ < 4; ++r_) {                                        \
        float Av_[3][4];                                                    \
        _Pragma("unroll")                                                   \
        for (int i_ = 0; i_ < 4; ++i_) {                                    \
            float z_  = (ACC)[0][i_][r_];                                   \
            float z1_ = (ACC)[1][i_][r_];                                   \
            float z2_ = (ACC)[2][i_][r_];                                   \
            float e_ = __expf(2.f * z_);                                    \
            float a_ = 1.f - 2.f * __builtin_amdgcn_rcpf(e_ + 1.f);         \
            float g_ = 1.f - a_ * a_;                                       \
            float d1_ = g_ * z1_;                                           \
            float d2_ = fmaf(g_, z2_, -2.f * a_ * d1_ * z1_);               \
            Av_[0][i_] = a_; Av_[1][i_] = d1_; Av_[2][i_] = d2_;            \
        }                                                                   \
        _Pragma("unroll")                                                   \
        for (int s_ = 0; s_ < 3; ++s_) {                                    \
            int2 hi2_;                                                      \
            hi2_.x = (int)pack_rne2(Av_[s_][0], Av_[s_][1]);                \
            hi2_.y = (int)pack_rne2(Av_[s_][2], Av_[s_][3]);                \
            *(int2*)&Ahi[s_ * TSTR + wbase_ + r_ * 8] = hi2_;               \
        }                                                                   \
    }                                                                       \
} while (0)

// ---- fused head for one group: transform in regs, dot W4, m16-reduce ----
#define HEAD(ACC, G) do {                                                   \
    float w4v_[4];                                                          \
    _Pragma("unroll")                                                       \
    for (int i_ = 0; i_ < 4; ++i_) w4v_[i_] = W4raw[w * 64 + i_ * 16 + m16];\
    float hp_[3][4];                                                        \
    _Pragma("unroll")                                                       \
    for (int s_ = 0; s_ < 3; ++s_)                                          \
        _Pragma("unroll")                                                   \
        for (int r_ = 0; r_ < 4; ++r_) hp_[s_][r_] = 0.f;                   \
    _Pragma("unroll")                                                       \
    for (int r_ = 0; r_ < 4; ++r_) {                                        \
        _Pragma("unroll")                                                   \
        for (int i_ = 0; i_ < 4; ++i_) {                                    \
            float z_  = (ACC)[0][i_][r_];                                   \
            float z1_ = (ACC)[1][i_][r_];                                   \
            float z2_ = (ACC)[2][i_][r_];                                   \
            float e_ = __expf(2.f * z_);                                    \
            float a_ = 1.f - 2.f * __builtin_amdgcn_rcpf(e_ + 1.f);         \
            float g_ = 1.f - a_ * a_;                                       \
            float d1_ = g_ * z1_;                                           \
            float d2_ = fmaf(g_, z2_, -2.f * a_ * d1_ * z1_);               \
            hp_[0][r_] = fmaf(w4v_[i_], a_,  hp_[0][r_]);                   \
            hp_[1][r_] = fmaf(w4v_[i_], d1_, hp_[1][r_]);                   \
            hp_[2][r_] = fmaf(w4v_[i_], d2_, hp_[2][r_]);                   \
        }                                                                   \
    }                                                                       \
    _Pragma("unroll")                                                       \
    for (int m_ = 1; m_ < 16; m_ <<= 1) {                                   \
        _Pragma("unroll")                                                   \
        for (int s_ = 0; s_ < 3; ++s_)                                      \
            _Pragma("unroll")                                               \
            for (int r_ = 0; r_ < 4; ++r_)                                  \
                hp_[s_][r_] += __shfl_xor(hp_[s_][r_], m_);                 \
    }                                                                       \
    if (m16 == 0) {                                                         \
        _Pragma("unroll")                                                   \
        for (int s_ = 0; s_ < 3; ++s_)                                      \
            _Pragma("unroll")                                               \
            for (int r_ = 0; r_ < 4; ++r_)                                  \
                head_part[G][(s_ * 16 + q * 4 + r_) * 4 + w] = hp_[s_][r_]; \
    }                                                                       \
} while (0)

// ---- main fused kernel: 2-group intra-block pipeline. Every barrier
// interval contains BOTH an MFMA cluster (group X, layer L) and a transform
// (group Y, layer L-1) for the same 256 threads -> MFMA and VALU pipes are
// co-fed within one block (R3 lesson: cross-block drift alone never mixed
// them; phases were pipe-pure). setprio(1) wraps only MFMA (role-split).
__global__ __launch_bounds__(NTHREADS, 3)
void capnn_mfma(const float* __restrict__ inp,
                const float* __restrict__ b1, const float* __restrict__ b2,
                const float* __restrict__ b3, const float* __restrict__ b4,
                const float* __restrict__ W4raw,
                const float* __restrict__ lgr, const float* __restrict__ lcc,
                const float* __restrict__ lil,
                const float* __restrict__ imean, const float* __restrict__ istd,
                const float* __restrict__ tmean, const float* __restrict__ tstd,
                const unsigned short* __restrict__ wsW,
                const float* __restrict__ wsF,
                float* __restrict__ out, int N)
{
    __shared__ __align__(16) unsigned short Ahi[2 * PLANE];   // 49.9 KB
    __shared__ float sn_sh[TP], tn_sh[TP];
    __shared__ float head_part[2][16 * 3 * 4];   // [group][(s*16+p)*4 + w]

    const int tid  = threadIdx.x;
    const int lane = tid & 63;
    const int w    = tid >> 6;      // 0..3: feature block of 64
    const int m16  = lane & 15;
    const int q    = lane >> 4;
    const int pbase = blockIdx.x * TP;

    const float* __restrict__ w00p = wsF;
    const float* __restrict__ w01p = wsF + 256;
    const float* __restrict__ b0p  = wsF + 512;

    if (tid < TP) {
        int pg = pbase + tid;
        float s = 0.f, t = 0.f;
        if (pg < N) { s = inp[2 * pg]; t = inp[2 * pg + 1]; }
        sn_sh[tid] = (s - imean[0]) / (istd[0] + 1e-8f);
        tn_sh[tid] = (t - imean[1]) / (istd[1] + 1e-8f);
    }
    __syncthreads();

    // ---- P0: layer 0 for BOTH groups (pure VALU + LDS writes) ----
    {
        const int l  = lane;
        const int p16 = l & 15, quad = l >> 4;
        #pragma unroll
        for (int g2 = 0; g2 < 2; ++g2) {
            const int ks = w + 4 * g2;
            const int pos = (ks * 4 + quad) * 8;
            float4 wA0 = *(const float4*)(w00p + pos);
            float4 wA1 = *(const float4*)(w00p + pos + 4);
            float4 wB0 = *(const float4*)(w01p + pos);
            float4 wB1 = *(const float4*)(w01p + pos + 4);
            float4 bb0 = *(const float4*)(b0p + pos);
            float4 bb1 = *(const float4*)(b0p + pos + 4);
            float w00v[8] = {wA0.x,wA0.y,wA0.z,wA0.w,wA1.x,wA1.y,wA1.z,wA1.w};
            float w01v[8] = {wB0.x,wB0.y,wB0.z,wB0.w,wB1.x,wB1.y,wB1.z,wB1.w};
            float b0v[8]  = {bb0.x,bb0.y,bb0.z,bb0.w,bb1.x,bb1.y,bb1.z,bb1.w};
            const int base = ks * KSTR + l * 8;
            #pragma unroll
            for (int h = 0; h < 2; ++h) {
                const float sn = sn_sh[h * 16 + p16];
                const float tn = tn_sh[h * 16 + p16];
                float av[8], d1v[8], d2v[8];
                #pragma unroll
                for (int j = 0; j < 8; ++j) {
                    float z = fmaf(w00v[j], sn, fmaf(w01v[j], tn, b0v[j]));
                    float e = __expf(2.f * z);
                    float a = 1.f - 2.f * __builtin_amdgcn_rcpf(e + 1.f);
                    float g = 1.f - a * a;
                    float d1 = g * w01v[j];
                    float d2 = -2.f * a * d1 * w01v[j];
                    av[j] = a; d1v[j] = d1; d2v[j] = d2;
                }
                #pragma unroll
                for (int s = 0; s < 3; ++s) {
                    const float* V = (s == 0) ? av : (s == 1) ? d1v : d2v;
                    int4 hi4;
                    hi4.x = (int)pack_rne2(V[0], V[1]);
                    hi4.y = (int)pack_rne2(V[2], V[3]);
                    hi4.z = (int)pack_rne2(V[4], V[5]);
                    hi4.w = (int)pack_rne2(V[6], V[7]);
                    *(int4*)&Ahi[h * PLANE + s * TSTR + base] = hi4;
                }
            }
        }
    }
    __syncthreads();

    f4v accA[NTILES][4], accB[NTILES][4];
    const unsigned short* __restrict__ W1h = wsW;
    const unsigned short* __restrict__ W2h = wsW + 65536;
    const unsigned short* __restrict__ W3h = wsW + 131072;

    // P1: cold start — MFMA(A, L1) alone
    MFMA_LAYER(accA, 0, W1h, b1);
    __syncthreads();
    // P2: MFMA(B, L1) || T(A <- L1)
    MFMA_LAYER(accB, PLANE, W1h, b1);
    TRANSFORM(accA, 0);
    __syncthreads();
    // P3: MFMA(A, L2) || T(B <- L1)
    MFMA_LAYER(accA, 0, W2h, b2);
    TRANSFORM(accB, PLANE);
    __syncthreads();
    // P4: MFMA(B, L2) || T(A <- L2)
    MFMA_LAYER(accB, PLANE, W2h, b2);
    TRANSFORM(accA, 0);
    __syncthreads();
    // P5: MFMA(A, L3) || T(B <- L2)
    MFMA_LAYER(accA, 0, W3h, b3);
    TRANSFORM(accB, PLANE);
    __syncthreads();
    // P6: MFMA(B, L3) || head(A)
    MFMA_LAYER(accB, PLANE, W3h, b3);
    HEAD(accA, 0);
    __syncthreads();
    // P7: head(B) — short exposed tail
    HEAD(accB, 1);
    __syncthreads();

    // ---- Verhulst residuals + store (both groups) ----
    if (tid < TP) {
        const int g = tid >> 4;
        const int p = tid & 15;
        float sv = 0.f, s1v = 0.f, s2v = 0.f;
        #pragma unroll
        for (int ww = 0; ww < 4; ++ww) {
            sv  += head_part[g][(0 * 16 + p) * 4 + ww];
            s1v += head_part[g][(1 * 16 + p) * 4 + ww];
            s2v += head_part[g][(2 * 16 + p) * 4 + ww];
        }
        int pg = pbase + tid;
        if (pg < N) {
            float r_  = expf(-lgr[0]);
            float Kc  = 0.2f + 0.8f / (1.f + expf(-lcc[0]));
            float Cc  = 0.1f / (1.f + expf(-lil[0]));
            float kci = 1.f / (Kc - Cc);
            float ts = tstd[0], tm = tmean[0];
            float U   = (sv + b4[0]) * ts + tm;
            float Ut  = s1v * ts;
            float Utt = s2v * ts;
            float Um  = U - Cc;
            float G   = r_ * Um * (1.f - Um * kci);
            float Gt  = r_ * Ut * (1.f - 2.f * Um * kci);
            out[pg]         = U;
            out[N + pg]     = Ut - G;
            out[2 * N + pg] = Utt - Gt;
        }
    }
}

extern "C" void kernel_launch(void* const* d_in, const int* in_sizes, int n_in,
                              void* d_out, int out_size, void* d_ws, size_t ws_size,
                              hipStream_t stream) {
    const float* inp   = (const float*)d_in[0];
    const float* W0    = (const float*)d_in[1];
    const float* b0    = (const float*)d_in[2];
    const float* W1    = (const float*)d_in[3];
    const float* b1    = (const float*)d_in[4];
    const float* W2    = (const float*)d_in[5];
    const float* b2    = (const float*)d_in[6];
    const float* W3    = (const float*)d_in[7];
    const float* b3    = (const float*)d_in[8];
    const float* W4    = (const float*)d_in[9];
    const float* b4    = (const float*)d_in[10];
    const float* lgr   = (const float*)d_in[11];
    const float* lcc   = (const float*)d_in[12];
    const float* lil   = (const float*)d_in[13];
    const float* imean = (const float*)d_in[14];
    const float* istd  = (const float*)d_in[15];
    const float* tmean = (const float*)d_in[16];
    const float* tstd  = (const float*)d_in[17];

    unsigned short* wsB = (unsigned short*)d_ws;            // 384 KB B-frags (RNE bf16)
    float* wsF = (float*)((char*)d_ws + 393216);            // 4 KB pi-planes

    const int N = in_sizes[0] / 2;
    const int gridMain = (N + TP - 1) / TP;                 // 2048 blocks

    hipLaunchKernelGGL(prep_weights, dim3(97), dim3(256), 0, stream,
                       W1, W2, W3, W0, b0, W4, wsB, wsF);
    hipLaunchKernelGGL(capnn_mfma, dim3(gridMain), dim3(NTHREADS), 0, stream,
                       inp, b1, b2, b3, b4, W4,
                       lgr, lcc, lil, imean, istd, tmean, tstd,
                       wsB, wsF, (float*)d_out, N);
}

// Round 5
// 184.535 us; speedup vs baseline: 1.0594x; 1.0594x over previous
//
#include <hip/hip_runtime.h>
#include <hip/hip_bf16.h>
#include <math.h>

typedef short s8v __attribute__((ext_vector_type(8)));
typedef float f4v __attribute__((ext_vector_type(4)));

#define HH 256
#define TP 16              // points per block
#define NTHREADS 256
// LDS strides in SHORTS. ks-chunk = 64 rows * 8 shorts + 8 pad = 520 (1040 B;
// 16 B rotation per ks spreads banks -> conflict-free scatter writes)
#define KSTR 520
#define TSTR 4160          // 8 * KSTR: one A-tile (16 pts x 256 feats, frag-linear)
#define NTILES 3           // 3 streams x 1 point-group per plane
#define PLANE (NTILES * TSTR)   // 12480 shorts = 25.0 KB; 2 planes = 49.9 KB

__device__ __forceinline__ unsigned short bf_rne(float x){
    union{float f;unsigned u;}v; v.f=x;
    unsigned r = v.u + 0x7FFFu + ((v.u >> 16) & 1u);
    return (unsigned short)(r >> 16);
}
// RNE-pack two floats -> packed bf16x2 (lowers to v_cvt_pk_bf16_f32 on gfx950)
__device__ __forceinline__ unsigned pack_rne2(float a, float b){
    union { __hip_bfloat162 h; unsigned u; } v;
    v.h = __float22bfloat162_rn(float2{a, b});
    return v.u;
}

// ---- prep: B-fragments for W1..W3 (single RNE bf16 plane) with k-permutation
// pi folded in, plus pi-ordered fp32 planes for W0 cols, b0.  (unchanged)
__global__ __launch_bounds__(256)
void prep_weights(const float* __restrict__ W1, const float* __restrict__ W2,
                  const float* __restrict__ W3, const float* __restrict__ W0,
                  const float* __restrict__ b0, const float* __restrict__ W4,
                  unsigned short* __restrict__ wsB, float* __restrict__ wsF)
{
    int t = blockIdx.x * 256 + threadIdx.x;
    if (t < 24576) {
        int layer = t >> 13;
        int rem = t & 8191;
        int l  = rem & 63;
        int ks = (rem >> 6) & 7;
        int nt = rem >> 9;
        const float* W = (layer == 0) ? W1 : (layer == 1) ? W2 : W3;
        int n_out = nt * 16 + (l & 15);
        int quad  = l >> 4;
        const float* row = W + n_out * HH;
        s8v hi;
        #pragma unroll
        for (int j = 0; j < 8; ++j) {
            int n_in = quad * 64 + (j & 3) * 16 + ((j >> 2) << 3) + ks;
            hi[j] = (short)bf_rne(row[n_in]);
        }
        int dst = ((nt * 8 + ks) * 64 + l) * 8;
        *(s8v*)(wsB + layer * 65536 + dst) = hi;
    } else if (t < 24832) {
        int n = t - 24576;
        int pos = ((n & 7) * 4 + (n >> 6)) * 8 + ((n >> 4) & 3) + 4 * ((n >> 3) & 1);
        wsF[pos]       = W0[2 * n];
        wsF[256 + pos] = W0[2 * n + 1];
        wsF[512 + pos] = b0[n];
        wsF[768 + pos] = W4[n];
    }
}

// ---- MFMA for one layer: reads plane at short-base RB; B-frags software-
// pipelined one ks ahead (L2 latency ~200cyc > 58cyc MFMA shadow per ks).
#define MFMA_LAYER(ACC, RB, WLH, BL) do {                                   \
    _Pragma("unroll")                                                       \
    for (int i_ = 0; i_ < 4; ++i_) {                                        \
        float bias_ = (BL)[w * 64 + i_ * 16 + m16];                         \
        (ACC)[0][i_] = (f4v){bias_, bias_, bias_, bias_};                   \
        (ACC)[1][i_] = (f4v){0.f, 0.f, 0.f, 0.f};                          \
        (ACC)[2][i_] = (f4v){0.f, 0.f, 0.f, 0.f};                          \
    }                                                                       \
    s8v bc0_ = *(const s8v*)((WLH) + (((w * 4 + 0) * 8 + 0) * 64 + lane) * 8); \
    s8v bc1_ = *(const s8v*)((WLH) + (((w * 4 + 1) * 8 + 0) * 64 + lane) * 8); \
    s8v bc2_ = *(const s8v*)((WLH) + (((w * 4 + 2) * 8 + 0) * 64 + lane) * 8); \
    s8v bc3_ = *(const s8v*)((WLH) + (((w * 4 + 3) * 8 + 0) * 64 + lane) * 8); \
    __builtin_amdgcn_s_setprio(1);                                          \
    _Pragma("unroll")                                                       \
    for (int ks_ = 0; ks_ < 8; ++ks_) {                                     \
        const int kn_ = (ks_ < 7) ? ks_ + 1 : ks_;                          \
        s8v bn0_ = *(const s8v*)((WLH) + (((w * 4 + 0) * 8 + kn_) * 64 + lane) * 8); \
        s8v bn1_ = *(const s8v*)((WLH) + (((w * 4 + 1) * 8 + kn_) * 64 + lane) * 8); \
        s8v bn2_ = *(const s8v*)((WLH) + (((w * 4 + 2) * 8 + kn_) * 64 + lane) * 8); \
        s8v bn3_ = *(const s8v*)((WLH) + (((w * 4 + 3) * 8 + kn_) * 64 + lane) * 8); \
        const int aoff_ = (RB) + ks_ * KSTR + lane * 8;                     \
        s8v ah0_ = *(const s8v*)&Ahi[0 * TSTR + aoff_];                     \
        s8v ah1_ = *(const s8v*)&Ahi[1 * TSTR + aoff_];                     \
        s8v ah2_ = *(const s8v*)&Ahi[2 * TSTR + aoff_];                     \
        (ACC)[0][0] = __builtin_amdgcn_mfma_f32_16x16x32_bf16(ah0_, bc0_, (ACC)[0][0], 0, 0, 0); \
        (ACC)[1][0] = __builtin_amdgcn_mfma_f32_16x16x32_bf16(ah1_, bc0_, (ACC)[1][0], 0, 0, 0); \
        (ACC)[2][0] = __builtin_amdgcn_mfma_f32_16x16x32_bf16(ah2_, bc0_, (ACC)[2][0], 0, 0, 0); \
        (ACC)[0][1] = __builtin_amdgcn_mfma_f32_16x16x32_bf16(ah0_, bc1_, (ACC)[0][1], 0, 0, 0); \
        (ACC)[1][1] = __builtin_amdgcn_mfma_f32_16x16x32_bf16(ah1_, bc1_, (ACC)[1][1], 0, 0, 0); \
        (ACC)[2][1] = __builtin_amdgcn_mfma_f32_16x16x32_bf16(ah2_, bc1_, (ACC)[2][1], 0, 0, 0); \
        (ACC)[0][2] = __builtin_amdgcn_mfma_f32_16x16x32_bf16(ah0_, bc2_, (ACC)[0][2], 0, 0, 0); \
        (ACC)[1][2] = __builtin_amdgcn_mfma_f32_16x16x32_bf16(ah1_, bc2_, (ACC)[1][2], 0, 0, 0); \
        (ACC)[2][2] = __builtin_amdgcn_mfma_f32_16x16x32_bf16(ah2_, bc2_, (ACC)[2][2], 0, 0, 0); \
        (ACC)[0][3] = __builtin_amdgcn_mfma_f32_16x16x32_bf16(ah0_, bc3_, (ACC)[0][3], 0, 0, 0); \
        (ACC)[1][3] = __builtin_amdgcn_mfma_f32_16x16x32_bf16(ah1_, bc3_, (ACC)[1][3], 0, 0, 0); \
        (ACC)[2][3] = __builtin_amdgcn_mfma_f32_16x16x32_bf16(ah2_, bc3_, (ACC)[2][3], 0, 0, 0); \
        bc0_ = bn0_; bc1_ = bn1_; bc2_ = bn2_; bc3_ = bn3_;                 \
    }                                                                       \
    __builtin_amdgcn_s_setprio(0);                                          \
} while (0)

// ---- tanh-transform of acc + pi-scatter into plane at short-base WB ----
// (writes the OTHER plane than the one just read -> no pre-transform barrier)
#define TRANSFORM(ACC, WB) do {                                             \
    const int ksw_  = m16 & 7;                                              \
    const int hsel_ = m16 >> 3;                                             \
    const int wbase_ = (WB) + ksw_ * KSTR + (16 * w + q * 4) * 8 + 4 * hsel_; \
    _Pragma("unroll")                                                       \
    for (int r_ = 0; r_ < 4; ++r_) {                                        \
        float Av_[3][4];                                                    \
        _Pragma("unroll")                                                   \
        for (int i_ = 0; i_ < 4; ++i_) {                                    \
            float z_  = (ACC)[0][i_][r_];                                   \
            float z1_ = (ACC)[1][i_][r_];                                   \
            float z2_ = (ACC)[2][i_][r_];                                   \
            float e_ = __expf(2.f * z_);                                    \
            float a_ = 1.f - 2.f * __builtin_amdgcn_rcpf(e_ + 1.f);         \
            float g_ = 1.f - a_ * a_;                                       \
            float d1_ = g_ * z1_;                                           \
            float d2_ = fmaf(g_, z2_, -2.f * a_ * d1_ * z1_);               \
            Av_[0][i_] = a_; Av_[1][i_] = d1_; Av_[2][i_] = d2_;            \
        }                                                                   \
        _Pragma("unroll")                                                   \
        for (int s_ = 0; s_ < 3; ++s_) {                                    \
            int2 hi2_;                                                      \
            hi2_.x = (int)pack_rne2(Av_[s_][0], Av_[s_][1]);                \
            hi2_.y = (int)pack_rne2(Av_[s_][2], Av_[s_][3]);                \
            *(int2*)&Ahi[s_ * TSTR + wbase_ + r_ * 8] = hi2_;               \
        }                                                                   \
    }                                                                       \
} while (0)

// ---- main fused kernel: TP=16, double-buffered A-planes (50 KB LDS),
// 5 barriers/block (was 8): L0 -> p0 | MFMA(L1) reads p0, T1 -> p1 | MFMA(L2)
// reads p1, T2 -> p0 | MFMA(L3) reads p0, head in regs. The removed
// pre-transform barriers let early waves transform (VALU) while late waves
// still MFMA (skew overlap). B-frags pipelined 1 ks ahead (L2 latency).
// Budgets: 48 AGPR acc + ~90 VGPR <= 170 cap (256,3); LDS 50.8K -> 3 blocks/CU.
__global__ __launch_bounds__(NTHREADS, 3)
void capnn_mfma(const float* __restrict__ inp,
                const float* __restrict__ b1, const float* __restrict__ b2,
                const float* __restrict__ b3, const float* __restrict__ b4,
                const float* __restrict__ W4raw,
                const float* __restrict__ lgr, const float* __restrict__ lcc,
                const float* __restrict__ lil,
                const float* __restrict__ imean, const float* __restrict__ istd,
                const float* __restrict__ tmean, const float* __restrict__ tstd,
                const unsigned short* __restrict__ wsW,
                const float* __restrict__ wsF,
                float* __restrict__ out, int N)
{
    __shared__ __align__(16) unsigned short Ahi[2 * PLANE];   // 49.9 KB
    __shared__ float sn_sh[TP], tn_sh[TP];
    __shared__ float head_part[TP * 3 * 4];   // [(s*16+p)*4 + w]

    const int tid  = threadIdx.x;
    const int lane = tid & 63;
    const int w    = tid >> 6;      // 0..3: feature block of 64
    const int m16  = lane & 15;
    const int q    = lane >> 4;
    const int pbase = blockIdx.x * TP;

    const float* __restrict__ w00p = wsF;
    const float* __restrict__ w01p = wsF + 256;
    const float* __restrict__ b0p  = wsF + 512;

    if (tid < TP) {
        int pg = pbase + tid;
        float s = 0.f, t = 0.f;
        if (pg < N) { s = inp[2 * pg]; t = inp[2 * pg + 1]; }
        sn_sh[tid] = (s - imean[0]) / (istd[0] + 1e-8f);
        tn_sh[tid] = (t - imean[1]) / (istd[1] + 1e-8f);
    }
    __syncthreads();                                   // B1

    // ---- layer 0 -> plane 0: thread <-> (ks = w+4g, row l) ----
    {
        const int l  = lane;
        const int p16 = l & 15, quad = l >> 4;
        const float sn = sn_sh[p16], tn = tn_sh[p16];
        #pragma unroll
        for (int g2 = 0; g2 < 2; ++g2) {
            const int ks = w + 4 * g2;
            const int pos = (ks * 4 + quad) * 8;
            float4 wA0 = *(const float4*)(w00p + pos);
            float4 wA1 = *(const float4*)(w00p + pos + 4);
            float4 wB0 = *(const float4*)(w01p + pos);
            float4 wB1 = *(const float4*)(w01p + pos + 4);
            float4 bb0 = *(const float4*)(b0p + pos);
            float4 bb1 = *(const float4*)(b0p + pos + 4);
            float w00v[8] = {wA0.x,wA0.y,wA0.z,wA0.w,wA1.x,wA1.y,wA1.z,wA1.w};
            float w01v[8] = {wB0.x,wB0.y,wB0.z,wB0.w,wB1.x,wB1.y,wB1.z,wB1.w};
            float b0v[8]  = {bb0.x,bb0.y,bb0.z,bb0.w,bb1.x,bb1.y,bb1.z,bb1.w};
            const int base = ks * KSTR + l * 8;
            float av[8], d1v[8], d2v[8];
            #pragma unroll
            for (int j = 0; j < 8; ++j) {
                float z = fmaf(w00v[j], sn, fmaf(w01v[j], tn, b0v[j]));
                float e = __expf(2.f * z);
                float a = 1.f - 2.f * __builtin_amdgcn_rcpf(e + 1.f);
                float g = 1.f - a * a;
                float d1 = g * w01v[j];
                float d2 = -2.f * a * d1 * w01v[j];
                av[j] = a; d1v[j] = d1; d2v[j] = d2;
            }
            #pragma unroll
            for (int s = 0; s < 3; ++s) {
                const float* V = (s == 0) ? av : (s == 1) ? d1v : d2v;
                int4 hi4;
                hi4.x = (int)pack_rne2(V[0], V[1]);
                hi4.y = (int)pack_rne2(V[2], V[3]);
                hi4.z = (int)pack_rne2(V[4], V[5]);
                hi4.w = (int)pack_rne2(V[6], V[7]);
                *(int4*)&Ahi[s * TSTR + base] = hi4;
            }
        }
    }
    __syncthreads();                                   // B2

    f4v acc[NTILES][4];
    const unsigned short* __restrict__ W1h = wsW;
    const unsigned short* __restrict__ W2h = wsW + 65536;
    const unsigned short* __restrict__ W3h = wsW + 131072;

    // L1: read p0, transform -> p1 (no barrier between: disjoint planes)
    MFMA_LAYER(acc, 0, W1h, b1);
    TRANSFORM(acc, PLANE);
    __syncthreads();                                   // B3

    // L2: read p1, transform -> p0
    MFMA_LAYER(acc, PLANE, W2h, b2);
    TRANSFORM(acc, 0);
    __syncthreads();                                   // B4

    // L3: read p0, fused head in regs
    MFMA_LAYER(acc, 0, W3h, b3);
    {
        float w4v[4];
        #pragma unroll
        for (int i = 0; i < 4; ++i) w4v[i] = W4raw[w * 64 + i * 16 + m16];

        float hp[3][4];
        #pragma unroll
        for (int s = 0; s < 3; ++s)
            #pragma unroll
            for (int r = 0; r < 4; ++r) hp[s][r] = 0.f;
        #pragma unroll
        for (int r = 0; r < 4; ++r) {
            #pragma unroll
            for (int i = 0; i < 4; ++i) {
                float z  = acc[0][i][r];
                float z1 = acc[1][i][r];
                float z2 = acc[2][i][r];
                float e = __expf(2.f * z);
                float a = 1.f - 2.f * __builtin_amdgcn_rcpf(e + 1.f);
                float g = 1.f - a * a;
                float d1 = g * z1;
                float d2 = fmaf(g, z2, -2.f * a * d1 * z1);
                hp[0][r] = fmaf(w4v[i], a,  hp[0][r]);
                hp[1][r] = fmaf(w4v[i], d1, hp[1][r]);
                hp[2][r] = fmaf(w4v[i], d2, hp[2][r]);
            }
        }
        #pragma unroll
        for (int m = 1; m < 16; m <<= 1) {
            #pragma unroll
            for (int s = 0; s < 3; ++s)
                #pragma unroll
                for (int r = 0; r < 4; ++r)
                    hp[s][r] += __shfl_xor(hp[s][r], m);
        }
        if (m16 == 0) {
            #pragma unroll
            for (int s = 0; s < 3; ++s)
                #pragma unroll
                for (int r = 0; r < 4; ++r)
                    head_part[(s * TP + q * 4 + r) * 4 + w] = hp[s][r];
        }
    }
    __syncthreads();                                   // B5

    // ---- Verhulst residuals + store ----
    if (tid < TP) {
        float sv = 0.f, s1v = 0.f, s2v = 0.f;
        #pragma unroll
        for (int ww = 0; ww < 4; ++ww) {
            sv  += head_part[(0 * TP + tid) * 4 + ww];
            s1v += head_part[(1 * TP + tid) * 4 + ww];
            s2v += head_part[(2 * TP + tid) * 4 + ww];
        }
        int pg = pbase + tid;
        if (pg < N) {
            float r_  = expf(-lgr[0]);
            float Kc  = 0.2f + 0.8f / (1.f + expf(-lcc[0]));
            float Cc  = 0.1f / (1.f + expf(-lil[0]));
            float kci = 1.f / (Kc - Cc);
            float ts = tstd[0], tm = tmean[0];
            float U   = (sv + b4[0]) * ts + tm;
            float Ut  = s1v * ts;
            float Utt = s2v * ts;
            float Um  = U - Cc;
            float G   = r_ * Um * (1.f - Um * kci);
            float Gt  = r_ * Ut * (1.f - 2.f * Um * kci);
            out[pg]         = U;
            out[N + pg]     = Ut - G;
            out[2 * N + pg] = Utt - Gt;
        }
    }
}

extern "C" void kernel_launch(void* const* d_in, const int* in_sizes, int n_in,
                              void* d_out, int out_size, void* d_ws, size_t ws_size,
                              hipStream_t stream) {
    const float* inp   = (const float*)d_in[0];
    const float* W0    = (const float*)d_in[1];
    const float* b0    = (const float*)d_in[2];
    const float* W1    = (const float*)d_in[3];
    const float* b1    = (const float*)d_in[4];
    const float* W2    = (const float*)d_in[5];
    const float* b2    = (const float*)d_in[6];
    const float* W3    = (const float*)d_in[7];
    const float* b3    = (const float*)d_in[8];
    const float* W4    = (const float*)d_in[9];
    const float* b4    = (const float*)d_in[10];
    const float* lgr   = (const float*)d_in[11];
    const float* lcc   = (const float*)d_in[12];
    const float* lil   = (const float*)d_in[13];
    const float* imean = (const float*)d_in[14];
    const float* istd  = (const float*)d_in[15];
    const float* tmean = (const float*)d_in[16];
    const float* tstd  = (const float*)d_in[17];

    unsigned short* wsB = (unsigned short*)d_ws;            // 384 KB B-frags (RNE bf16)
    float* wsF = (float*)((char*)d_ws + 393216);            // 4 KB pi-planes

    const int N = in_sizes[0] / 2;
    const int gridMain = (N + TP - 1) / TP;                 // 4096 blocks

    hipLaunchKernelGGL(prep_weights, dim3(97), dim3(256), 0, stream,
                       W1, W2, W3, W0, b0, W4, wsB, wsF);
    hipLaunchKernelGGL(capnn_mfma, dim3(gridMain), dim3(NTHREADS), 0, stream,
                       inp, b1, b2, b3, b4, W4,
                       lgr, lcc, lil, imean, istd, tmean, tstd,
                       wsB, wsF, (float*)d_out, N);
}

// Round 6
// 183.533 us; speedup vs baseline: 1.0652x; 1.0055x over previous
//
#include <hip/hip_runtime.h>
#include <hip/hip_bf16.h>
#include <math.h>

typedef short s8v __attribute__((ext_vector_type(8)));
typedef float f4v __attribute__((ext_vector_type(4)));

#define HH 256
#define TP 16              // points per block
#define NTHREADS 256
// LDS strides in SHORTS. ks-chunk = 64 rows * 8 shorts + 8 pad = 520 (1040 B;
// 16 B rotation per ks spreads banks -> conflict-free scatter writes)
#define KSTR 520
#define TSTR 4160          // 8 * KSTR: one A-tile (16 pts x 256 feats, frag-linear)
#define NTILES 3           // 3 streams x 1 point-group per plane
#define PLANE (NTILES * TSTR)   // 12480 shorts = 25.0 KB; 2 planes = 49.9 KB

__device__ __forceinline__ unsigned short bf_rne(float x){
    union{float f;unsigned u;}v; v.f=x;
    unsigned r = v.u + 0x7FFFu + ((v.u >> 16) & 1u);
    return (unsigned short)(r >> 16);
}
// RNE-pack two floats -> packed bf16x2 (lowers to v_cvt_pk_bf16_f32 on gfx950)
__device__ __forceinline__ unsigned pack_rne2(float a, float b){
    union { __hip_bfloat162 h; unsigned u; } v;
    v.h = __float22bfloat162_rn(float2{a, b});
    return v.u;
}

// ---- prep: B-fragments for W1..W3 (single RNE bf16 plane) with k-permutation
// pi folded in, plus pi-ordered fp32 planes for W0 cols, b0.  (unchanged)
__global__ __launch_bounds__(256)
void prep_weights(const float* __restrict__ W1, const float* __restrict__ W2,
                  const float* __restrict__ W3, const float* __restrict__ W0,
                  const float* __restrict__ b0, const float* __restrict__ W4,
                  unsigned short* __restrict__ wsB, float* __restrict__ wsF)
{
    int t = blockIdx.x * 256 + threadIdx.x;
    if (t < 24576) {
        int layer = t >> 13;
        int rem = t & 8191;
        int l  = rem & 63;
        int ks = (rem >> 6) & 7;
        int nt = rem >> 9;
        const float* W = (layer == 0) ? W1 : (layer == 1) ? W2 : W3;
        int n_out = nt * 16 + (l & 15);
        int quad  = l >> 4;
        const float* row = W + n_out * HH;
        s8v hi;
        #pragma unroll
        for (int j = 0; j < 8; ++j) {
            int n_in = quad * 64 + (j & 3) * 16 + ((j >> 2) << 3) + ks;
            hi[j] = (short)bf_rne(row[n_in]);
        }
        int dst = ((nt * 8 + ks) * 64 + l) * 8;
        *(s8v*)(wsB + layer * 65536 + dst) = hi;
    } else if (t < 24832) {
        int n = t - 24576;
        int pos = ((n & 7) * 4 + (n >> 6)) * 8 + ((n >> 4) & 3) + 4 * ((n >> 3) & 1);
        wsF[pos]       = W0[2 * n];
        wsF[256 + pos] = W0[2 * n + 1];
        wsF[512 + pos] = b0[n];
        wsF[768 + pos] = W4[n];
    }
}

// ---- MFMA for one layer, reading plane at short-base RB.
// Deep software pipeline against load latency (R5 lesson: the kernel is
// latency-bound — idle ~60%, matrix pipe near-saturated while running):
//   B-frags (L2, ~200-225 cyc): depth-3, 4 rotating slots (ks and ks+3 must
//   not alias -> %4). A-frags (LDS, ~120 cyc): depth-1, 2 slots.
// Full unroll makes every slot index compile-time (rule #20: no scratch).
#define MFMA_LAYER(ACC, RB, WLH, BL) do {                                   \
    _Pragma("unroll")                                                       \
    for (int i_ = 0; i_ < 4; ++i_) {                                        \
        float bias_ = (BL)[w * 64 + i_ * 16 + m16];                         \
        (ACC)[0][i_] = (f4v){bias_, bias_, bias_, bias_};                   \
        (ACC)[1][i_] = (f4v){0.f, 0.f, 0.f, 0.f};                          \
        (ACC)[2][i_] = (f4v){0.f, 0.f, 0.f, 0.f};                          \
    }                                                                       \
    s8v Bv_[4][4];                                                          \
    s8v Av_[2][3];                                                          \
    _Pragma("unroll")                                                       \
    for (int p_ = 0; p_ < 3; ++p_)                                          \
        _Pragma("unroll")                                                   \
        for (int i_ = 0; i_ < 4; ++i_)                                      \
            Bv_[p_][i_] = *(const s8v*)((WLH) +                             \
                (((w * 4 + i_) * 8 + p_) * 64 + lane) * 8);                 \
    {                                                                       \
        const int a0_ = (RB) + lane * 8;                                    \
        _Pragma("unroll")                                                   \
        for (int t_ = 0; t_ < 3; ++t_)                                      \
            Av_[0][t_] = *(const s8v*)&Ahi[t_ * TSTR + a0_];                \
    }                                                                       \
    __builtin_amdgcn_s_setprio(1);                                          \
    _Pragma("unroll")                                                       \
    for (int ks_ = 0; ks_ < 8; ++ks_) {                                     \
        if (ks_ + 1 < 8) {                                                  \
            const int an_ = (RB) + (ks_ + 1) * KSTR + lane * 8;             \
            _Pragma("unroll")                                               \
            for (int t_ = 0; t_ < 3; ++t_)                                  \
                Av_[(ks_ + 1) & 1][t_] = *(const s8v*)&Ahi[t_ * TSTR + an_];\
        }                                                                   \
        if (ks_ + 3 < 8) {                                                  \
            _Pragma("unroll")                                               \
            for (int i_ = 0; i_ < 4; ++i_)                                  \
                Bv_[(ks_ + 3) & 3][i_] = *(const s8v*)((WLH) +              \
                    (((w * 4 + i_) * 8 + (ks_ + 3)) * 64 + lane) * 8);      \
        }                                                                   \
        _Pragma("unroll")                                                   \
        for (int i_ = 0; i_ < 4; ++i_) {                                    \
            _Pragma("unroll")                                               \
            for (int t_ = 0; t_ < 3; ++t_)                                  \
                (ACC)[t_][i_] = __builtin_amdgcn_mfma_f32_16x16x32_bf16(    \
                    Av_[ks_ & 1][t_], Bv_[ks_ & 3][i_], (ACC)[t_][i_],      \
                    0, 0, 0);                                               \
        }                                                                   \
    }                                                                       \
    __builtin_amdgcn_s_setprio(0);                                          \
} while (0)

// ---- tanh-transform of acc + pi-scatter into plane at short-base WB ----
// (writes the OTHER plane than the one just read -> no pre-transform barrier)
#define TRANSFORM(ACC, WB) do {                                             \
    const int ksw_  = m16 & 7;                                              \
    const int hsel_ = m16 >> 3;                                             \
    const int wbase_ = (WB) + ksw_ * KSTR + (16 * w + q * 4) * 8 + 4 * hsel_; \
    _Pragma("unroll")                                                       \
    for (int r_ = 0; r_ < 4; ++r_) {                                        \
        float Av_[3][4];                                                    \
        _Pragma("unroll")                                                   \
        for (int i_ = 0; i_ < 4; ++i_) {                                    \
            float z_  = (ACC)[0][i_][r_];                                   \
            float z1_ = (ACC)[1][i_][r_];                                   \
            float z2_ = (ACC)[2][i_][r_];                                   \
            float e_ = __expf(2.f * z_);                                    \
            float a_ = 1.f - 2.f * __builtin_amdgcn_rcpf(e_ + 1.f);         \
            float g_ = 1.f - a_ * a_;                                       \
            float d1_ = g_ * z1_;                                           \
            float d2_ = fmaf(g_, z2_, -2.f * a_ * d1_ * z1_);               \
            Av_[0][i_] = a_; Av_[1][i_] = d1_; Av_[2][i_] = d2_;            \
        }                                                                   \
        _Pragma("unroll")                                                   \
        for (int s_ = 0; s_ < 3; ++s_) {                                    \
            int2 hi2_;                                                      \
            hi2_.x = (int)pack_rne2(Av_[s_][0], Av_[s_][1]);                \
            hi2_.y = (int)pack_rne2(Av_[s_][2], Av_[s_][3]);                \
            *(int2*)&Ahi[s_ * TSTR + wbase_ + r_ * 8] = hi2_;               \
        }                                                                   \
    }                                                                       \
} while (0)

// ---- main fused kernel: TP=16, double-buffered A-planes (50 KB LDS),
// 5 barriers/block. Deep-pipelined MFMA (see MFMA_LAYER). Budgets:
// ~118 VGPR + 48 AGPR ~= 166 <= 170 cap (256,3); LDS 50.8K -> 3 blocks/CU.
__global__ __launch_bounds__(NTHREADS, 3)
void capnn_mfma(const float* __restrict__ inp,
                const float* __restrict__ b1, const float* __restrict__ b2,
                const float* __restrict__ b3, const float* __restrict__ b4,
                const float* __restrict__ W4raw,
                const float* __restrict__ lgr, const float* __restrict__ lcc,
                const float* __restrict__ lil,
                const float* __restrict__ imean, const float* __restrict__ istd,
                const float* __restrict__ tmean, const float* __restrict__ tstd,
                const unsigned short* __restrict__ wsW,
                const float* __restrict__ wsF,
                float* __restrict__ out, int N)
{
    __shared__ __align__(16) unsigned short Ahi[2 * PLANE];   // 49.9 KB
    __shared__ float sn_sh[TP], tn_sh[TP];
    __shared__ float head_part[TP * 3 * 4];   // [(s*16+p)*4 + w]

    const int tid  = threadIdx.x;
    const int lane = tid & 63;
    const int w    = tid >> 6;      // 0..3: feature block of 64
    const int m16  = lane & 15;
    const int q    = lane >> 4;
    const int pbase = blockIdx.x * TP;

    const float* __restrict__ w00p = wsF;
    const float* __restrict__ w01p = wsF + 256;
    const float* __restrict__ b0p  = wsF + 512;

    if (tid < TP) {
        int pg = pbase + tid;
        float s = 0.f, t = 0.f;
        if (pg < N) { s = inp[2 * pg]; t = inp[2 * pg + 1]; }
        sn_sh[tid] = (s - imean[0]) / (istd[0] + 1e-8f);
        tn_sh[tid] = (t - imean[1]) / (istd[1] + 1e-8f);
    }
    __syncthreads();                                   // B1

    // ---- layer 0 -> plane 0: thread <-> (ks = w+4g, row l) ----
    {
        const int l  = lane;
        const int p16 = l & 15, quad = l >> 4;
        const float sn = sn_sh[p16], tn = tn_sh[p16];
        #pragma unroll
        for (int g2 = 0; g2 < 2; ++g2) {
            const int ks = w + 4 * g2;
            const int pos = (ks * 4 + quad) * 8;
            float4 wA0 = *(const float4*)(w00p + pos);
            float4 wA1 = *(const float4*)(w00p + pos + 4);
            float4 wB0 = *(const float4*)(w01p + pos);
            float4 wB1 = *(const float4*)(w01p + pos + 4);
            float4 bb0 = *(const float4*)(b0p + pos);
            float4 bb1 = *(const float4*)(b0p + pos + 4);
            float w00v[8] = {wA0.x,wA0.y,wA0.z,wA0.w,wA1.x,wA1.y,wA1.z,wA1.w};
            float w01v[8] = {wB0.x,wB0.y,wB0.z,wB0.w,wB1.x,wB1.y,wB1.z,wB1.w};
            float b0v[8]  = {bb0.x,bb0.y,bb0.z,bb0.w,bb1.x,bb1.y,bb1.z,bb1.w};
            const int base = ks * KSTR + l * 8;
            float av[8], d1v[8], d2v[8];
            #pragma unroll
            for (int j = 0; j < 8; ++j) {
                float z = fmaf(w00v[j], sn, fmaf(w01v[j], tn, b0v[j]));
                float e = __expf(2.f * z);
                float a = 1.f - 2.f * __builtin_amdgcn_rcpf(e + 1.f);
                float g = 1.f - a * a;
                float d1 = g * w01v[j];
                float d2 = -2.f * a * d1 * w01v[j];
                av[j] = a; d1v[j] = d1; d2v[j] = d2;
            }
            #pragma unroll
            for (int s = 0; s < 3; ++s) {
                const float* V = (s == 0) ? av : (s == 1) ? d1v : d2v;
                int4 hi4;
                hi4.x = (int)pack_rne2(V[0], V[1]);
                hi4.y = (int)pack_rne2(V[2], V[3]);
                hi4.z = (int)pack_rne2(V[4], V[5]);
                hi4.w = (int)pack_rne2(V[6], V[7]);
                *(int4*)&Ahi[s * TSTR + base] = hi4;
            }
        }
    }
    __syncthreads();                                   // B2

    f4v acc[NTILES][4];
    const unsigned short* __restrict__ W1h = wsW;
    const unsigned short* __restrict__ W2h = wsW + 65536;
    const unsigned short* __restrict__ W3h = wsW + 131072;

    // L1: read p0, transform -> p1 (no barrier between: disjoint planes)
    MFMA_LAYER(acc, 0, W1h, b1);
    TRANSFORM(acc, PLANE);
    __syncthreads();                                   // B3

    // L2: read p1, transform -> p0
    MFMA_LAYER(acc, PLANE, W2h, b2);
    TRANSFORM(acc, 0);
    __syncthreads();                                   // B4

    // L3: read p0, fused head in regs
    MFMA_LAYER(acc, 0, W3h, b3);
    {
        float w4v[4];
        #pragma unroll
        for (int i = 0; i < 4; ++i) w4v[i] = W4raw[w * 64 + i * 16 + m16];

        float hp[3][4];
        #pragma unroll
        for (int s = 0; s < 3; ++s)
            #pragma unroll
            for (int r = 0; r < 4; ++r) hp[s][r] = 0.f;
        #pragma unroll
        for (int r = 0; r < 4; ++r) {
            #pragma unroll
            for (int i = 0; i < 4; ++i) {
                float z  = acc[0][i][r];
                float z1 = acc[1][i][r];
                float z2 = acc[2][i][r];
                float e = __expf(2.f * z);
                float a = 1.f - 2.f * __builtin_amdgcn_rcpf(e + 1.f);
                float g = 1.f - a * a;
                float d1 = g * z1;
                float d2 = fmaf(g, z2, -2.f * a * d1 * z1);
                hp[0][r] = fmaf(w4v[i], a,  hp[0][r]);
                hp[1][r] = fmaf(w4v[i], d1, hp[1][r]);
                hp[2][r] = fmaf(w4v[i], d2, hp[2][r]);
            }
        }
        #pragma unroll
        for (int m = 1; m < 16; m <<= 1) {
            #pragma unroll
            for (int s = 0; s < 3; ++s)
                #pragma unroll
                for (int r = 0; r < 4; ++r)
                    hp[s][r] += __shfl_xor(hp[s][r], m);
        }
        if (m16 == 0) {
            #pragma unroll
            for (int s = 0; s < 3; ++s)
                #pragma unroll
                for (int r = 0; r < 4; ++r)
                    head_part[(s * TP + q * 4 + r) * 4 + w] = hp[s][r];
        }
    }
    __syncthreads();                                   // B5

    // ---- Verhulst residuals + store ----
    if (tid < TP) {
        float sv = 0.f, s1v = 0.f, s2v = 0.f;
        #pragma unroll
        for (int ww = 0; ww < 4; ++ww) {
            sv  += head_part[(0 * TP + tid) * 4 + ww];
            s1v += head_part[(1 * TP + tid) * 4 + ww];
            s2v += head_part[(2 * TP + tid) * 4 + ww];
        }
        int pg = pbase + tid;
        if (pg < N) {
            float r_  = expf(-lgr[0]);
            float Kc  = 0.2f + 0.8f / (1.f + expf(-lcc[0]));
            float Cc  = 0.1f / (1.f + expf(-lil[0]));
            float kci = 1.f / (Kc - Cc);
            float ts = tstd[0], tm = tmean[0];
            float U   = (sv + b4[0]) * ts + tm;
            float Ut  = s1v * ts;
            float Utt = s2v * ts;
            float Um  = U - Cc;
            float G   = r_ * Um * (1.f - Um * kci);
            float Gt  = r_ * Ut * (1.f - 2.f * Um * kci);
            out[pg]         = U;
            out[N + pg]     = Ut - G;
            out[2 * N + pg] = Utt - Gt;
        }
    }
}

extern "C" void kernel_launch(void* const* d_in, const int* in_sizes, int n_in,
                              void* d_out, int out_size, void* d_ws, size_t ws_size,
                              hipStream_t stream) {
    const float* inp   = (const float*)d_in[0];
    const float* W0    = (const float*)d_in[1];
    const float* b0    = (const float*)d_in[2];
    const float* W1    = (const float*)d_in[3];
    const float* b1    = (const float*)d_in[4];
    const float* W2    = (const float*)d_in[5];
    const float* b2    = (const float*)d_in[6];
    const float* W3    = (const float*)d_in[7];
    const float* b3    = (const float*)d_in[8];
    const float* W4    = (const float*)d_in[9];
    const float* b4    = (const float*)d_in[10];
    const float* lgr   = (const float*)d_in[11];
    const float* lcc   = (const float*)d_in[12];
    const float* lil   = (const float*)d_in[13];
    const float* imean = (const float*)d_in[14];
    const float* istd  = (const float*)d_in[15];
    const float* tmean = (const float*)d_in[16];
    const float* tstd  = (const float*)d_in[17];

    unsigned short* wsB = (unsigned short*)d_ws;            // 384 KB B-frags (RNE bf16)
    float* wsF = (float*)((char*)d_ws + 393216);            // 4 KB pi-planes

    const int N = in_sizes[0] / 2;
    const int gridMain = (N + TP - 1) / TP;                 // 4096 blocks

    hipLaunchKernelGGL(prep_weights, dim3(97), dim3(256), 0, stream,
                       W1, W2, W3, W0, b0, W4, wsB, wsF);
    hipLaunchKernelGGL(capnn_mfma, dim3(gridMain), dim3(NTHREADS), 0, stream,
                       inp, b1, b2, b3, b4, W4,
                       lgr, lcc, lil, imean, istd, tmean, tstd,
                       wsB, wsF, (float*)d_out, N);
}